// Round 4
// baseline (234.285 us; speedup 1.0000x reference)
//
#include <hip/hip_runtime.h>
#include <math.h>

#define BB 32
#define VV 2048
#define PP 64
#define AA 8
#define NFF 128
#define FF 72          // P + A
#define TWOF 144       // 2*F

// ---------------------------------------------------------------------------
// k1: feats = [x@W1+b1, exp(-|x@W2+b2|)]  -> featsT [B][F][V], agg [B][V][A]
// one thread per vertex; weights in LDS (broadcast reads)
// ---------------------------------------------------------------------------
__global__ __launch_bounds__(256) void k1_feats(
        const float* __restrict__ x,
        const float* __restrict__ W1, const float* __restrict__ b1,
        const float* __restrict__ W2, const float* __restrict__ b2,
        float* __restrict__ featsT, float* __restrict__ agg) {
    __shared__ float Wc[64][80];   // f<64: W1[p][f]; f>=64: W2[p][f-64]; pad 80
    __shared__ float bias[72];

    const int b = blockIdx.y;
    const int v = blockIdx.x * 256 + threadIdx.x;

    for (int i = threadIdx.x; i < 64 * 72; i += 256) {
        int p = i / 72, f = i % 72;
        Wc[p][f] = (f < 64) ? W1[p * 64 + f] : W2[p * 8 + (f - 64)];
    }
    if (threadIdx.x < 72)
        bias[threadIdx.x] = (threadIdx.x < 64) ? b1[threadIdx.x] : b2[threadIdx.x - 64];
    __syncthreads();

    // load x row into registers (compile-time indexed only)
    float xs[64];
    const float4* xp = reinterpret_cast<const float4*>(x + ((size_t)b * VV + v) * PP);
    #pragma unroll
    for (int i = 0; i < 16; ++i) {
        float4 t = xp[i];
        xs[4 * i + 0] = t.x; xs[4 * i + 1] = t.y; xs[4 * i + 2] = t.z; xs[4 * i + 3] = t.w;
    }

    // vi outputs: chunks c = 0..15  (f = 4c..4c+3)
    for (int c = 0; c < 16; ++c) {
        float4 acc = make_float4(bias[4 * c + 0], bias[4 * c + 1], bias[4 * c + 2], bias[4 * c + 3]);
        #pragma unroll
        for (int p = 0; p < 64; ++p) {
            const float4 w = *reinterpret_cast<const float4*>(&Wc[p][4 * c]);
            const float xv = xs[p];
            acc.x += xv * w.x; acc.y += xv * w.y; acc.z += xv * w.z; acc.w += xv * w.w;
        }
        float* fr = featsT + ((size_t)b * FF + 4 * c) * VV + v;
        fr[0 * VV] = acc.x; fr[1 * VV] = acc.y; fr[2 * VV] = acc.z; fr[3 * VV] = acc.w;
    }

    // agg outputs: chunks 16,17 (f = 64..71), explicit so ex[] is static-indexed
    float ex[8];
    #pragma unroll
    for (int cc = 0; cc < 2; ++cc) {
        const int c = 16 + cc;
        float4 acc = make_float4(bias[4 * c + 0], bias[4 * c + 1], bias[4 * c + 2], bias[4 * c + 3]);
        #pragma unroll
        for (int p = 0; p < 64; ++p) {
            const float4 w = *reinterpret_cast<const float4*>(&Wc[p][4 * c]);
            const float xv = xs[p];
            acc.x += xv * w.x; acc.y += xv * w.y; acc.z += xv * w.z; acc.w += xv * w.w;
        }
        acc.x = __expf(-fabsf(acc.x));
        acc.y = __expf(-fabsf(acc.y));
        acc.z = __expf(-fabsf(acc.z));
        acc.w = __expf(-fabsf(acc.w));
        float* fr = featsT + ((size_t)b * FF + 4 * c) * VV + v;
        fr[0 * VV] = acc.x; fr[1 * VV] = acc.y; fr[2 * VV] = acc.z; fr[3 * VV] = acc.w;
        ex[4 * cc + 0] = acc.x; ex[4 * cc + 1] = acc.y; ex[4 * cc + 2] = acc.z; ex[4 * cc + 3] = acc.w;
    }

    float4* ap = reinterpret_cast<float4*>(agg + ((size_t)b * VV + v) * AA);
    ap[0] = make_float4(ex[0], ex[1], ex[2], ex[3]);
    ap[1] = make_float4(ex[4], ex[5], ex[6], ex[7]);
}

// ---------------------------------------------------------------------------
// k2: reduce over V: mx/mn of agg[b,v,a]*feats[b,v,f] -> collapsed [B][A][2F]
// block = (f-group of 8, b); thread-serial v accumulation, lane = v (coalesced)
// ---------------------------------------------------------------------------
__global__ __launch_bounds__(256) void k2_reduce(
        const float* __restrict__ featsT, const float* __restrict__ agg,
        float* __restrict__ collapsed) {
    const int fg = blockIdx.x;      // 0..8
    const int b  = blockIdx.y;
    const int f0 = fg * 8;
    const int t  = threadIdx.x;
    const int wave = t >> 6, lane = t & 63;

    __shared__ float redm[4][64];
    __shared__ float reds[4][64];

    float pmax[8][8], psum[8][8];
    #pragma unroll
    for (int j = 0; j < 8; ++j)
        #pragma unroll
        for (int a = 0; a < 8; ++a) { pmax[j][a] = -INFINITY; psum[j][a] = 0.0f; }

    for (int i = 0; i < 8; ++i) {
        const int v = i * 256 + t;
        const float4* ep = reinterpret_cast<const float4*>(agg + ((size_t)b * VV + v) * AA);
        const float4 e0 = ep[0], e1 = ep[1];
        float e[8];
        e[0] = e0.x; e[1] = e0.y; e[2] = e0.z; e[3] = e0.w;
        e[4] = e1.x; e[5] = e1.y; e[6] = e1.z; e[7] = e1.w;
        #pragma unroll
        for (int j = 0; j < 8; ++j) {
            const float fv = featsT[((size_t)b * FF + f0 + j) * VV + v];
            #pragma unroll
            for (int a = 0; a < 8; ++a) {
                const float pr = e[a] * fv;
                pmax[j][a] = fmaxf(pmax[j][a], pr);
                psum[j][a] += pr;
            }
        }
    }

    // 64-lane butterfly, then lane 0 of each wave stashes to LDS
    #pragma unroll
    for (int j = 0; j < 8; ++j) {
        #pragma unroll
        for (int a = 0; a < 8; ++a) {
            float m = pmax[j][a];
            float s = psum[j][a];
            #pragma unroll
            for (int d = 1; d < 64; d <<= 1) {
                m = fmaxf(m, __shfl_xor(m, d));
                s += __shfl_xor(s, d);
            }
            if (lane == 0) { redm[wave][j * 8 + a] = m; reds[wave][j * 8 + a] = s; }
        }
    }
    __syncthreads();

    if (t < 64) {
        const int j = t >> 3, a = t & 7;
        float m = redm[0][t], s = reds[0][t];
        #pragma unroll
        for (int w = 1; w < 4; ++w) { m = fmaxf(m, redm[w][t]); s += reds[w][t]; }
        float* cr = collapsed + ((size_t)b * AA + a) * TWOF;
        cr[f0 + j]      = m;
        cr[FF + f0 + j] = s * (1.0f / (float)VV);
    }
}

// ---------------------------------------------------------------------------
// k2b: M'[b][a][nf] = Wout[1216+a][nf] + sum_g collapsed[b][a][g]*Wout[64+a*144+g][nf]
// ---------------------------------------------------------------------------
__global__ __launch_bounds__(128) void k2b_mprime(
        const float* __restrict__ collapsed, const float* __restrict__ Wout,
        float* __restrict__ Mp) {
    const int a = blockIdx.x, b = blockIdx.y, nf = threadIdx.x;
    const float* col = collapsed + ((size_t)b * AA + a) * TWOF;
    float acc = Wout[(size_t)(1216 + a) * NFF + nf];
    #pragma unroll 4
    for (int g = 0; g < TWOF; ++g)
        acc += col[g] * Wout[(size_t)(64 + a * TWOF + g) * NFF + nf];
    Mp[((size_t)b * AA + a) * NFF + nf] = acc;
}

// ---------------------------------------------------------------------------
// k3: out = tanh(x@Wtop + agg@M'[b] + bout)  -> [B][V][NF]
// one thread per vertex; Wtop + M'[b] in LDS (broadcast reads)
// ---------------------------------------------------------------------------
__device__ __forceinline__ float fast_tanh(float z) {
    const float e = __expf(2.0f * z);
    return 1.0f - 2.0f / (e + 1.0f);
}

__global__ __launch_bounds__(256) void k3_out(
        const float* __restrict__ x, const float* __restrict__ agg,
        const float* __restrict__ Mp, const float* __restrict__ Wout,
        const float* __restrict__ bout, float* __restrict__ out) {
    __shared__ float Wt[64][NFF];   // 32 KB, rows 0..63 of Wout
    __shared__ float Ml[8][NFF];    // 4 KB
    __shared__ float bo[NFF];

    const int b = blockIdx.y;
    const int v = blockIdx.x * 256 + threadIdx.x;

    for (int i = threadIdx.x; i < 64 * NFF; i += 256) Wt[i / NFF][i % NFF] = Wout[i];
    for (int i = threadIdx.x; i < 8 * NFF; i += 256)  Ml[i / NFF][i % NFF] = Mp[(size_t)b * AA * NFF + i];
    if (threadIdx.x < NFF) bo[threadIdx.x] = bout[threadIdx.x];
    __syncthreads();

    float xs[64];
    const float4* xp = reinterpret_cast<const float4*>(x + ((size_t)b * VV + v) * PP);
    #pragma unroll
    for (int i = 0; i < 16; ++i) {
        float4 t = xp[i];
        xs[4 * i + 0] = t.x; xs[4 * i + 1] = t.y; xs[4 * i + 2] = t.z; xs[4 * i + 3] = t.w;
    }
    float e[8];
    const float4* ep = reinterpret_cast<const float4*>(agg + ((size_t)b * VV + v) * AA);
    {
        const float4 e0 = ep[0], e1 = ep[1];
        e[0] = e0.x; e[1] = e0.y; e[2] = e0.z; e[3] = e0.w;
        e[4] = e1.x; e[5] = e1.y; e[6] = e1.z; e[7] = e1.w;
    }

    float4* op = reinterpret_cast<float4*>(out + ((size_t)b * VV + v) * NFF);
    for (int c = 0; c < 32; ++c) {
        float4 acc = *reinterpret_cast<const float4*>(&bo[4 * c]);
        #pragma unroll
        for (int p = 0; p < 64; ++p) {
            const float4 w = *reinterpret_cast<const float4*>(&Wt[p][4 * c]);
            const float xv = xs[p];
            acc.x += xv * w.x; acc.y += xv * w.y; acc.z += xv * w.z; acc.w += xv * w.w;
        }
        #pragma unroll
        for (int a = 0; a < 8; ++a) {
            const float4 w = *reinterpret_cast<const float4*>(&Ml[a][4 * c]);
            const float ea = e[a];
            acc.x += ea * w.x; acc.y += ea * w.y; acc.z += ea * w.z; acc.w += ea * w.w;
        }
        acc.x = fast_tanh(acc.x); acc.y = fast_tanh(acc.y);
        acc.z = fast_tanh(acc.z); acc.w = fast_tanh(acc.w);
        op[c] = acc;
    }
}

// ---------------------------------------------------------------------------
extern "C" void kernel_launch(void* const* d_in, const int* in_sizes, int n_in,
                              void* d_out, int out_size, void* d_ws, size_t ws_size,
                              hipStream_t stream) {
    const float* x    = (const float*)d_in[0];
    const float* W1   = (const float*)d_in[1];
    const float* b1   = (const float*)d_in[2];
    const float* W2   = (const float*)d_in[3];
    const float* b2   = (const float*)d_in[4];
    const float* Wout = (const float*)d_in[5];
    const float* bout = (const float*)d_in[6];
    float* out = (float*)d_out;

    float* ws     = (float*)d_ws;
    float* featsT = ws;                                   // B*F*V   = 4,718,592
    float* agg    = featsT + (size_t)BB * FF * VV;        // B*V*A   =   524,288
    float* coll   = agg + (size_t)BB * VV * AA;           // B*A*2F  =    36,864
    float* Mp     = coll + (size_t)BB * AA * TWOF;        // B*A*NF  =    32,768

    k1_feats<<<dim3(8, 32), dim3(256), 0, stream>>>(x, W1, b1, W2, b2, featsT, agg);
    k2_reduce<<<dim3(9, 32), dim3(256), 0, stream>>>(featsT, agg, coll);
    k2b_mprime<<<dim3(8, 32), dim3(128), 0, stream>>>(coll, Wout, Mp);
    k3_out<<<dim3(8, 32), dim3(256), 0, stream>>>(x, agg, Mp, Wout, bout, out);
}

// Round 6
// 169.922 us; speedup vs baseline: 1.3788x; 1.3788x over previous
//
#include <hip/hip_runtime.h>
#include <math.h>

#define BB 32
#define VV 2048
#define PP 64
#define AA 8
#define NFF 128
#define FF 72          // P + A
#define TWOF 144       // 2*F

// ---------------------------------------------------------------------------
// k1: feats = [x@W1+b1, exp(-|x@W2+b2|)]  -> featsT [B][F][V], agg [B][V][A]
// one thread per vertex; f-dim split x3 across blockIdx.z for occupancy
// ---------------------------------------------------------------------------
__global__ __launch_bounds__(256) void k1_feats(
        const float* __restrict__ x,
        const float* __restrict__ W1, const float* __restrict__ b1,
        const float* __restrict__ W2, const float* __restrict__ b2,
        float* __restrict__ featsT, float* __restrict__ agg) {
    __shared__ float Wc[64][24];   // 24-feature slice; rows 96 B (16B-aligned)
    __shared__ float biasl[24];

    const int b  = blockIdx.y;
    const int fg = blockIdx.z;             // 0..2, features fg*24 .. fg*24+23
    const int fbase = fg * 24;
    const int v  = blockIdx.x * 256 + threadIdx.x;

    for (int i = threadIdx.x; i < 64 * 24; i += 256) {
        int p = i / 24, fl = i % 24, f = fbase + fl;
        Wc[p][fl] = (f < 64) ? W1[p * 64 + f] : W2[p * 8 + (f - 64)];
    }
    if (threadIdx.x < 24) {
        int f = fbase + threadIdx.x;
        biasl[threadIdx.x] = (f < 64) ? b1[f] : b2[f - 64];
    }
    __syncthreads();

    // load x row into registers (compile-time indexed only)
    float xs[64];
    const float4* xp = reinterpret_cast<const float4*>(x + ((size_t)b * VV + v) * PP);
    #pragma unroll
    for (int i = 0; i < 16; ++i) {
        float4 t = xp[i];
        xs[4 * i + 0] = t.x; xs[4 * i + 1] = t.y; xs[4 * i + 2] = t.z; xs[4 * i + 3] = t.w;
    }

    float ex[8];   // only used by fg==2 (global f 64..71 = local chunks 4,5)

    #pragma unroll
    for (int c = 0; c < 6; ++c) {
        float4 acc = make_float4(biasl[4 * c + 0], biasl[4 * c + 1],
                                 biasl[4 * c + 2], biasl[4 * c + 3]);
        #pragma unroll
        for (int p = 0; p < 64; ++p) {
            const float4 w = *reinterpret_cast<const float4*>(&Wc[p][4 * c]);
            const float xv = xs[p];
            acc.x += xv * w.x; acc.y += xv * w.y; acc.z += xv * w.z; acc.w += xv * w.w;
        }
        const int f = fbase + 4 * c;
        if (f >= 64) {  // uniform branch (fg==2, c>=4): gauss_of_lin
            acc.x = __expf(-fabsf(acc.x));
            acc.y = __expf(-fabsf(acc.y));
            acc.z = __expf(-fabsf(acc.z));
            acc.w = __expf(-fabsf(acc.w));
            const int a0 = f - 64;          // 0 or 4
            if (a0 == 0) { ex[0] = acc.x; ex[1] = acc.y; ex[2] = acc.z; ex[3] = acc.w; }
            else         { ex[4] = acc.x; ex[5] = acc.y; ex[6] = acc.z; ex[7] = acc.w; }
        }
        float* fr = featsT + ((size_t)b * FF + f) * VV + v;
        fr[0 * VV] = acc.x; fr[1 * VV] = acc.y; fr[2 * VV] = acc.z; fr[3 * VV] = acc.w;
    }

    if (fg == 2) {
        float4* ap = reinterpret_cast<float4*>(agg + ((size_t)b * VV + v) * AA);
        ap[0] = make_float4(ex[0], ex[1], ex[2], ex[3]);
        ap[1] = make_float4(ex[4], ex[5], ex[6], ex[7]);
    }
}

// ---------------------------------------------------------------------------
// k2: reduce over V: mx/mn of agg[b,v,a]*feats[b,v,f] -> collapsed [B][A][2F]
// block = (f-group of 4, b); thread-serial v accumulation, lane = v (coalesced)
// ---------------------------------------------------------------------------
__global__ __launch_bounds__(256) void k2_reduce(
        const float* __restrict__ featsT, const float* __restrict__ agg,
        float* __restrict__ collapsed) {
    const int fg = blockIdx.x;      // 0..17
    const int b  = blockIdx.y;
    const int f0 = fg * 4;
    const int t  = threadIdx.x;
    const int wave = t >> 6, lane = t & 63;

    __shared__ float redm[4][32];
    __shared__ float reds[4][32];

    float pmax[4][8], psum[4][8];
    #pragma unroll
    for (int j = 0; j < 4; ++j)
        #pragma unroll
        for (int a = 0; a < 8; ++a) { pmax[j][a] = -INFINITY; psum[j][a] = 0.0f; }

    for (int i = 0; i < 8; ++i) {
        const int v = i * 256 + t;
        const float4* ep = reinterpret_cast<const float4*>(agg + ((size_t)b * VV + v) * AA);
        const float4 e0 = ep[0], e1 = ep[1];
        float e[8];
        e[0] = e0.x; e[1] = e0.y; e[2] = e0.z; e[3] = e0.w;
        e[4] = e1.x; e[5] = e1.y; e[6] = e1.z; e[7] = e1.w;
        #pragma unroll
        for (int j = 0; j < 4; ++j) {
            const float fv = featsT[((size_t)b * FF + f0 + j) * VV + v];
            #pragma unroll
            for (int a = 0; a < 8; ++a) {
                const float pr = e[a] * fv;
                pmax[j][a] = fmaxf(pmax[j][a], pr);
                psum[j][a] += pr;
            }
        }
    }

    // 64-lane butterfly, then lane 0 of each wave stashes to LDS
    #pragma unroll
    for (int j = 0; j < 4; ++j) {
        #pragma unroll
        for (int a = 0; a < 8; ++a) {
            float m = pmax[j][a];
            float s = psum[j][a];
            #pragma unroll
            for (int d = 1; d < 64; d <<= 1) {
                m = fmaxf(m, __shfl_xor(m, d));
                s += __shfl_xor(s, d);
            }
            if (lane == 0) { redm[wave][j * 8 + a] = m; reds[wave][j * 8 + a] = s; }
        }
    }
    __syncthreads();

    if (t < 32) {
        const int j = t >> 3, a = t & 7;
        float m = redm[0][t], s = reds[0][t];
        #pragma unroll
        for (int w = 1; w < 4; ++w) { m = fmaxf(m, redm[w][t]); s += reds[w][t]; }
        float* cr = collapsed + ((size_t)b * AA + a) * TWOF;
        cr[f0 + j]      = m;
        cr[FF + f0 + j] = s * (1.0f / (float)VV);
    }
}

// ---------------------------------------------------------------------------
// k2b: M'[b][a][nf] = Wout[1216+a][nf] + sum_g collapsed[b][a][g]*Wout[64+a*144+g][nf]
// ---------------------------------------------------------------------------
__global__ __launch_bounds__(128) void k2b_mprime(
        const float* __restrict__ collapsed, const float* __restrict__ Wout,
        float* __restrict__ Mp) {
    const int a = blockIdx.x, b = blockIdx.y, nf = threadIdx.x;
    const float* col = collapsed + ((size_t)b * AA + a) * TWOF;
    float acc = Wout[(size_t)(1216 + a) * NFF + nf];
    #pragma unroll 4
    for (int g = 0; g < TWOF; ++g)
        acc += col[g] * Wout[(size_t)(64 + a * TWOF + g) * NFF + nf];
    Mp[((size_t)b * AA + a) * NFF + nf] = acc;
}

// ---------------------------------------------------------------------------
// k3: out = tanh(x@Wtop + agg@M'[b] + bout)  -> [B][V][NF]
// one thread per vertex; nf-dim split x4 across blockIdx.z for occupancy
// ---------------------------------------------------------------------------
__device__ __forceinline__ float fast_tanh(float z) {
    const float e = __expf(2.0f * z);
    return 1.0f - 2.0f / (e + 1.0f);
}

__global__ __launch_bounds__(256) void k3_out(
        const float* __restrict__ x, const float* __restrict__ agg,
        const float* __restrict__ Mp, const float* __restrict__ Wout,
        const float* __restrict__ bout, float* __restrict__ out) {
    __shared__ float Wt[64][32];   // 8 KB: rows 0..63 of Wout, nf-quarter slice
    __shared__ float Ml[8][32];    // 1 KB
    __shared__ float bo[32];

    const int b = blockIdx.y;
    const int q = blockIdx.z;              // 0..3, nf range q*32 .. q*32+31
    const int n0 = q * 32;
    const int v = blockIdx.x * 256 + threadIdx.x;

    for (int i = threadIdx.x; i < 64 * 32; i += 256)
        Wt[i / 32][i % 32] = Wout[(size_t)(i / 32) * NFF + n0 + (i % 32)];
    for (int i = threadIdx.x; i < 8 * 32; i += 256)
        Ml[i / 32][i % 32] = Mp[(size_t)b * AA * NFF + (size_t)(i / 32) * NFF + n0 + (i % 32)];
    if (threadIdx.x < 32) bo[threadIdx.x] = bout[n0 + threadIdx.x];
    __syncthreads();

    float xs[64];
    const float4* xp = reinterpret_cast<const float4*>(x + ((size_t)b * VV + v) * PP);
    #pragma unroll
    for (int i = 0; i < 16; ++i) {
        float4 t = xp[i];
        xs[4 * i + 0] = t.x; xs[4 * i + 1] = t.y; xs[4 * i + 2] = t.z; xs[4 * i + 3] = t.w;
    }
    float e[8];
    const float4* ep = reinterpret_cast<const float4*>(agg + ((size_t)b * VV + v) * AA);
    {
        const float4 e0 = ep[0], e1 = ep[1];
        e[0] = e0.x; e[1] = e0.y; e[2] = e0.z; e[3] = e0.w;
        e[4] = e1.x; e[5] = e1.y; e[6] = e1.z; e[7] = e1.w;
    }

    float* op = out + ((size_t)b * VV + v) * NFF + n0;
    #pragma unroll
    for (int c = 0; c < 8; ++c) {
        float4 acc = *reinterpret_cast<const float4*>(&bo[4 * c]);
        #pragma unroll
        for (int p = 0; p < 64; ++p) {
            const float4 w = *reinterpret_cast<const float4*>(&Wt[p][4 * c]);
            const float xv = xs[p];
            acc.x += xv * w.x; acc.y += xv * w.y; acc.z += xv * w.z; acc.w += xv * w.w;
        }
        #pragma unroll
        for (int a = 0; a < 8; ++a) {
            const float4 w = *reinterpret_cast<const float4*>(&Ml[a][4 * c]);
            const float ea = e[a];
            acc.x += ea * w.x; acc.y += ea * w.y; acc.z += ea * w.z; acc.w += ea * w.w;
        }
        acc.x = fast_tanh(acc.x); acc.y = fast_tanh(acc.y);
        acc.z = fast_tanh(acc.z); acc.w = fast_tanh(acc.w);
        *reinterpret_cast<float4*>(&op[4 * c]) = acc;
    }
}

// ---------------------------------------------------------------------------
extern "C" void kernel_launch(void* const* d_in, const int* in_sizes, int n_in,
                              void* d_out, int out_size, void* d_ws, size_t ws_size,
                              hipStream_t stream) {
    const float* x    = (const float*)d_in[0];
    const float* W1   = (const float*)d_in[1];
    const float* b1   = (const float*)d_in[2];
    const float* W2   = (const float*)d_in[3];
    const float* b2   = (const float*)d_in[4];
    const float* Wout = (const float*)d_in[5];
    const float* bout = (const float*)d_in[6];
    float* out = (float*)d_out;

    float* ws     = (float*)d_ws;
    float* featsT = ws;                                   // B*F*V   = 4,718,592
    float* agg    = featsT + (size_t)BB * FF * VV;        // B*V*A   =   524,288
    float* coll   = agg + (size_t)BB * VV * AA;           // B*A*2F  =    36,864
    float* Mp     = coll + (size_t)BB * AA * TWOF;        // B*A*NF  =    32,768

    k1_feats<<<dim3(8, 32, 3), dim3(256), 0, stream>>>(x, W1, b1, W2, b2, featsT, agg);
    k2_reduce<<<dim3(18, 32), dim3(256), 0, stream>>>(featsT, agg, coll);
    k2b_mprime<<<dim3(8, 32), dim3(128), 0, stream>>>(coll, Wout, Mp);
    k3_out<<<dim3(8, 32, 4), dim3(256), 0, stream>>>(x, agg, Mp, Wout, bout, out);
}